// Round 11
// baseline (394.505 us; speedup 1.0000x reference)
//
#include <hip/hip_runtime.h>
#include <hip/hip_bf16.h>
#include <hip/hip_cooperative_groups.h>

namespace cg = cooperative_groups;

#define N_GRAPHS 200
#define NPG      500
#define NPGP     512                   // padded nodes per graph (MFMA tiles)
#define N_NODES_ 100000
#define N_EDGES_ 1600000
#define DIN      64
#define DG       128
#define SEQ      20
#define HL       128
#define G4       512
#define BWIN     (N_GRAPHS - SEQ + 1)  // 181
#define NPART    256
#define EPB      (N_EDGES_/NPART)      // 6250

typedef __attribute__((ext_vector_type(8))) short short8;
typedef __attribute__((ext_vector_type(4))) float float4v;
typedef __attribute__((ext_vector_type(2))) _Float16 half2v;

__device__ __forceinline__ float sigmoidf_(float v){ return 1.0f/(1.0f+expf(-v)); }

// fp32 -> bf16 round-to-nearest-even
__device__ __forceinline__ unsigned short f2bf(float f) {
  unsigned int u = __float_as_uint(f);
  u += 0x7fffu + ((u >> 16) & 1u);
  return (unsigned short)(u >> 16);
}

__device__ __forceinline__ float h2dot(half2v a, half2v b, float c) {
#if __has_builtin(__builtin_amdgcn_fdot2)
  return __builtin_amdgcn_fdot2(a, b, c, false);
#else
  return c + (float)a.x*(float)b.x + (float)a.y*(float)b.y;
#endif
}

// K1 (cooperative, grid=256x512): count -> scan -> partition -> per-graph
// counting sort (+e_end/e_deg) -> xprep. Replaces 5 kernels; the serial-launch
// overhead of the 9-kernel pipeline (~120 us of the 245) was the round-10
// bottleneck, not any single kernel.
__global__ __launch_bounds__(512) void k_prep(
    const int* __restrict__ src, const int* __restrict__ dst,
    const float* __restrict__ x,
    int* __restrict__ cnt, int* __restrict__ gtot, int* __restrict__ gbase,
    int* __restrict__ part, unsigned short* __restrict__ sorted_all,
    int* __restrict__ e_end, int* __restrict__ e_deg,
    ushort4* __restrict__ xsb) {
  cg::grid_group grid = cg::this_grid();
  __shared__ int sA[512], sB[512];
  __shared__ int bins[NPG];    // count bins(200) / part cursors(200) / sort indeg(500)
  __shared__ int bins2[NPG];   // sort outdeg
  __shared__ int off_[NPG];
  __shared__ float soS[NPG];
  int b = blockIdx.x, t = threadIdx.x;
  int e0 = b*EPB;

  // ---- phase 1: per-(block,graph) histogram ----
  for (int i = t; i < N_GRAPHS; i += 512) bins[i] = 0;
  __syncthreads();
  for (int i = t; i < EPB; i += 512) atomicAdd(&bins[src[e0+i]/NPG], 1);
  __syncthreads();
  for (int g = t; g < N_GRAPHS; g += 512) cnt[g*NPART + b] = bins[g];
  grid.sync();

  // ---- phase 2a: per-graph column sums (blocks 0..199) ----
  if (b < N_GRAPHS) {
    int v = (t < NPART) ? cnt[b*NPART + t] : 0;
    sA[t] = v; __syncthreads();
    for (int o = 256; o > 0; o >>= 1) { if (t < o) sA[t] += sA[t+o]; __syncthreads(); }
    if (t == 0) gtot[b] = sA[0];
  }
  grid.sync();

  // ---- phase 2b: block 0 exclusive scan of graph totals ----
  if (b == 0) {
    int v = (t < N_GRAPHS) ? gtot[t] : 0;
    sA[t] = v; __syncthreads();
    int* cur = sA; int* nxt = sB;
    for (int o = 1; o < 512; o <<= 1) {
      nxt[t] = cur[t] + ((t >= o) ? cur[t-o] : 0);
      __syncthreads();
      int* tmp = cur; cur = nxt; nxt = tmp;
    }
    if (t < N_GRAPHS) gbase[t] = cur[t] - v;
  }
  grid.sync();

  // ---- phase 2c: per-graph column exclusive offsets ----
  if (b < N_GRAPHS) {
    int v = (t < NPART) ? cnt[b*NPART + t] : 0;
    sA[t] = v; __syncthreads();
    int* cur = sA; int* nxt = sB;
    for (int o = 1; o < 512; o <<= 1) {
      nxt[t] = cur[t] + ((t >= o) ? cur[t-o] : 0);
      __syncthreads();
      int* tmp = cur; cur = nxt; nxt = tmp;
    }
    if (t < NPART) cnt[b*NPART + t] = gbase[b] + cur[t] - v;
  }
  grid.sync();

  // ---- phase 3: deterministic partition by graph ----
  for (int g = t; g < N_GRAPHS; g += 512) bins[g] = cnt[g*NPART + b];
  __syncthreads();
  for (int i = t; i < EPB; i += 512) {
    int s = src[e0+i], d = dst[e0+i];
    int g = s / NPG;
    int sl = s - g*NPG, dl = d - g*NPG;
    int pos = atomicAdd(&bins[g], 1);
    part[pos] = (sl << 9) | dl;
  }
  grid.sync();

  // ---- phase 4: per-graph counting sort + metadata + xprep (blocks 0..199) ----
  if (b < N_GRAPHS) {
    int g = b;
    int seg0 = cnt[g*NPART];
    int seg1 = (g == N_GRAPHS-1) ? N_EDGES_ : cnt[(g+1)*NPART];
    if (t < NPG) { bins[t] = 0; bins2[t] = 0; }   // indeg / outdeg
    __syncthreads();
    for (int e = seg0 + t; e < seg1; e += 512) {
      int p = part[e];
      atomicAdd(&bins[p & 511], 1);
      atomicAdd(&bins2[p >> 9], 1);
    }
    __syncthreads();
    int v = (t < NPG) ? bins[t] : 0;
    sA[t] = v; __syncthreads();
    int* cur = sA; int* nxt = sB;
    for (int o = 1; o < 512; o <<= 1) {
      nxt[t] = cur[t] + ((t >= o) ? cur[t-o] : 0);
      __syncthreads();
      int* tmp = cur; cur = nxt; nxt = tmp;
    }
    if (t < NPG) off_[t] = cur[t] - v;
    __syncthreads();
    for (int e = seg0 + t; e < seg1; e += 512) {
      int p = part[e];
      int pos = atomicAdd(&off_[p & 511], 1);
      sorted_all[seg0 + pos] = (unsigned short)(p >> 9);
    }
    __syncthreads();
    if (t < NPG) {
      soS[t] = rsqrtf((float)max(bins2[t], 1));
      e_end[g*NPG + t] = seg0 + off_[t];   // off_ now inclusive end
      e_deg[g*NPG + t] = bins[t];
    }
    __syncthreads();
    // xprep: xsb[n][k] = bf16(x[n][k] * so[n])
    const float4* xg = ((const float4*)x) + (size_t)g*8000;   // 500*16
    ushort4* og = xsb + (size_t)g*8000;
    for (int i = t; i < 8000; i += 512) {
      float4 vv = xg[i];
      float s = soS[i >> 4];
      ushort4 u;
      u.x = f2bf(vv.x*s); u.y = f2bf(vv.y*s); u.z = f2bf(vv.z*s); u.w = f2bf(vv.w*s);
      og[i] = u;
    }
  }
}

// K2: aggregation — wave per node slot; 8 lanes per edge (int4 = 8 bf16),
// 4-edge unroll per group (L2-latency bound: double the outstanding gathers).
// Packed-bf16 accumulate (exact). XCD swizzle: g % 8 == xcd.
__global__ __launch_bounds__(256) void k_agg(const int4* __restrict__ xsb,
    const int* __restrict__ e_end, const int* __restrict__ e_deg,
    const unsigned short* __restrict__ sorted_all,
    unsigned short* __restrict__ hpreb) {
  int b = blockIdx.x;
  int xcd = b & 7;
  int i_ = b >> 3;                       // 0..3199
  int g = (i_ >> 7)*8 + xcd;             // g % 8 == xcd
  int t = threadIdx.x;
  int nl = ((i_ & 127) << 2) + (t >> 6); // node slot 0..511 within graph
  int npad = g*NPGP + nl;
  int lane = t & 63, g8 = lane >> 3, fl = lane & 7;
  if (nl >= NPG) {                       // pad rows -> zeros
    if (g8 == 0) {
      int4 z = make_int4(0,0,0,0);
      ((int4*)hpreb)[(size_t)npad*8 + fl] = z;
    }
    return;
  }
  int n = g*NPG + nl;
  int end = e_end[n], deg = e_deg[n], start = end - deg;
  const int4* xg = xsb + (size_t)g*4000;      // 500 rows * 8 int4
  float aHi[4] = {0.f,0.f,0.f,0.f};
  float aLo[4] = {0.f,0.f,0.f,0.f};
  for (int i = start + (g8 << 2); i < end; i += 32) {
    int sj[4];
    #pragma unroll
    for (int j = 0; j < 4; ++j) sj[j] = (i + j < end) ? (int)sorted_all[i+j] : -1;
    #pragma unroll
    for (int j = 0; j < 4; ++j) if (sj[j] >= 0) {
      int4 v = xg[sj[j]*8 + fl];
      aHi[0] += __uint_as_float((unsigned)v.x & 0xffff0000u);
      aLo[0] += __uint_as_float((unsigned)v.x << 16);
      aHi[1] += __uint_as_float((unsigned)v.y & 0xffff0000u);
      aLo[1] += __uint_as_float((unsigned)v.y << 16);
      aHi[2] += __uint_as_float((unsigned)v.z & 0xffff0000u);
      aLo[2] += __uint_as_float((unsigned)v.z << 16);
      aHi[3] += __uint_as_float((unsigned)v.w & 0xffff0000u);
      aLo[3] += __uint_as_float((unsigned)v.w << 16);
    }
  }
  #pragma unroll
  for (int m = 8; m < 64; m <<= 1) {
    #pragma unroll
    for (int d = 0; d < 4; ++d) {
      aHi[d] += __shfl_xor(aHi[d], m);
      aLo[d] += __shfl_xor(aLo[d], m);
    }
  }
  if (g8 == 0) {
    float sn = rsqrtf((float)max(deg, 1));
    int4 outv;
    outv.x = (int)(((unsigned)f2bf(aLo[0]*sn)) | ((unsigned)f2bf(aHi[0]*sn) << 16));
    outv.y = (int)(((unsigned)f2bf(aLo[1]*sn)) | ((unsigned)f2bf(aHi[1]*sn) << 16));
    outv.z = (int)(((unsigned)f2bf(aLo[2]*sn)) | ((unsigned)f2bf(aHi[2]*sn) << 16));
    outv.w = (int)(((unsigned)f2bf(aLo[3]*sn)) | ((unsigned)f2bf(aHi[3]*sn) << 16));
    ((int4*)hpreb)[(size_t)npad*8 + fl] = outv;
  }
}

// K3: MFMA GCN GEMM + ReLU + mean pool + FUSED input projection.
// Block = one graph; hg lives only in LDS; proj written directly.
__global__ __launch_bounds__(256) void k_gcn(
    const unsigned short* __restrict__ hpreb,
    const float* __restrict__ w_gcn,
    const float* __restrict__ b_gcn,
    const float* __restrict__ w_ih,
    const float* __restrict__ b_ih,
    float* __restrict__ proj) {
  __shared__ unsigned short wLds[16*64*8];   // 16 KB
  __shared__ float pS[4*DG];
  __shared__ __align__(16) float hgS[DG];
  int t = threadIdx.x, g = blockIdx.x;
  for (int idx = t; idx < 16*64; idx += 256) {
    int f = idx >> 6, l = idx & 63;
    int h = f & 1, nt = f >> 1;
    int kbase = h*32 + (l >> 4)*8;
    int n = nt*16 + (l & 15);
    #pragma unroll
    for (int j = 0; j < 8; ++j)
      wLds[idx*8 + j] = f2bf(w_gcn[(kbase + j)*DG + n]);
  }
  __syncthreads();
  int w = t >> 6, lane = t & 63;
  int quad = lane >> 4, l15 = lane & 15;
  float bcol[8];
  #pragma unroll
  for (int nt = 0; nt < 8; ++nt) bcol[nt] = b_gcn[nt*16 + l15];
  float psum[8] = {0.f,0.f,0.f,0.f,0.f,0.f,0.f,0.f};
  const unsigned short* hb = hpreb + (size_t)g*NPGP*DIN;
  for (int i = 0; i < 8; ++i) {
    int rt = w + 4*i;
    int row0 = rt*16;
    const short8* aptr = (const short8*)(hb + (size_t)(row0 + l15)*DIN + quad*8);
    short8 a0 = aptr[0];
    short8 a1 = aptr[4];
    #pragma unroll
    for (int nt = 0; nt < 8; ++nt) {
      short8 b0 = *((const short8*)&wLds[((nt*2+0)*64 + lane)*8]);
      short8 b1 = *((const short8*)&wLds[((nt*2+1)*64 + lane)*8]);
      float4v acc = {0.f, 0.f, 0.f, 0.f};
      acc = __builtin_amdgcn_mfma_f32_16x16x32_bf16(a0, b0, acc, 0, 0, 0);
      acc = __builtin_amdgcn_mfma_f32_16x16x32_bf16(a1, b1, acc, 0, 0, 0);
      #pragma unroll
      for (int r = 0; r < 4; ++r) {
        int node = row0 + quad*4 + r;
        float v = acc[r] + bcol[nt];
        psum[nt] += (node < NPG) ? fmaxf(v, 0.f) : 0.f;
      }
    }
  }
  #pragma unroll
  for (int nt = 0; nt < 8; ++nt) {
    float v = psum[nt];
    v += __shfl_xor(v, 16);
    v += __shfl_xor(v, 32);
    if (lane < 16) pS[w*DG + nt*16 + lane] = v;
  }
  __syncthreads();
  if (t < DG)
    hgS[t] = (pS[t] + pS[DG+t] + pS[2*DG+t] + pS[3*DG+t]) * (1.0f/NPG);
  __syncthreads();
  // fused projection: proj[g][r] = w_ih[r,:].hg + b_ih[r]
  for (int r = t; r < G4; r += 256) {
    const float4* wr = (const float4*)(w_ih + (size_t)r*HL);
    const float4* hv = (const float4*)hgS;
    float acc = b_ih[r];
    #pragma unroll
    for (int k4 = 0; k4 < 32; ++k4) {
      float4 w4 = wr[k4]; float4 h4 = hv[k4];
      acc += w4.x*h4.x + w4.y*h4.y + w4.z*h4.z + w4.w*h4.w;
    }
    proj[(size_t)g*G4 + r] = acc;
  }
}

// K4: LSTM — w_hh fp16 CU-resident in LDS; h packed fp16; fp32 accumulation
// via v_dot2_f32_f16; gates/c fp32. (Round-10 verified: 44.6 -> <43 us.)
__global__ __launch_bounds__(512) void k_lstm(const float* __restrict__ proj,
    const float* __restrict__ w_hh, const float* __restrict__ b_hh,
    const float* __restrict__ w_fc, const float* __restrict__ b_fc,
    float* __restrict__ out) {
  __shared__ int4 wL[16*512];        // 128 KB: [k4][r] = 8 fp16 of w_hh[r][k4*8..]
  __shared__ float gS[G4];           // 2 KB
  __shared__ __align__(16) int4 hPi[16];  // 128 fp16 packed h state
  int b = blockIdx.x, t = threadIdx.x;
  for (int i = t; i < 16*512; i += 512) {
    int k4 = i >> 9, r = i & 511;
    const float4* wp = (const float4*)(w_hh + (size_t)r*HL + k4*8);
    float4 w0 = wp[0], w1 = wp[1];
    half2v p0 = {(_Float16)w0.x, (_Float16)w0.y};
    half2v p1 = {(_Float16)w0.z, (_Float16)w0.w};
    half2v p2 = {(_Float16)w1.x, (_Float16)w1.y};
    half2v p3 = {(_Float16)w1.z, (_Float16)w1.w};
    int4 pk;
    pk.x = __builtin_bit_cast(int, p0); pk.y = __builtin_bit_cast(int, p1);
    pk.z = __builtin_bit_cast(int, p2); pk.w = __builtin_bit_cast(int, p3);
    wL[i] = pk;
  }
  if (t < 16) hPi[t] = make_int4(0,0,0,0);
  float bh = b_hh[t];
  float c0 = 0.f, c1 = 0.f;
  __syncthreads();
  for (int l = 0; l < SEQ; ++l) {
    float acc = proj[(size_t)(b+l)*G4 + t] + bh;
    #pragma unroll
    for (int k4 = 0; k4 < 16; ++k4) {
      int4 wv = wL[(k4 << 9) + t];
      int4 hv = hPi[k4];
      acc = h2dot(__builtin_bit_cast(half2v, wv.x), __builtin_bit_cast(half2v, hv.x), acc);
      acc = h2dot(__builtin_bit_cast(half2v, wv.y), __builtin_bit_cast(half2v, hv.y), acc);
      acc = h2dot(__builtin_bit_cast(half2v, wv.z), __builtin_bit_cast(half2v, hv.z), acc);
      acc = h2dot(__builtin_bit_cast(half2v, wv.w), __builtin_bit_cast(half2v, hv.w), acc);
    }
    gS[t] = acc;
    __syncthreads();
    if (t < 64) {
      int j0 = 2*t, j1 = 2*t + 1;
      float i0 = sigmoidf_(gS[j0]),      i1 = sigmoidf_(gS[j1]);
      float f0 = sigmoidf_(gS[HL+j0]),   f1 = sigmoidf_(gS[HL+j1]);
      float g0 = tanhf(gS[2*HL+j0]),     g1 = tanhf(gS[2*HL+j1]);
      float o0 = sigmoidf_(gS[3*HL+j0]), o1 = sigmoidf_(gS[3*HL+j1]);
      c0 = f0*c0 + i0*g0;
      c1 = f1*c1 + i1*g1;
      float h0 = o0 * tanhf(c0);
      float h1 = o1 * tanhf(c1);
      half2v hp = {(_Float16)h0, (_Float16)h1};
      ((int*)hPi)[t] = __builtin_bit_cast(int, hp);
      if (l == SEQ-1) {
        float s = h0*w_fc[j0] + h1*w_fc[j1];
        #pragma unroll
        for (int off = 32; off > 0; off >>= 1) s += __shfl_down(s, off);
        if (t == 0) out[b] = s + b_fc[0];
      }
    }
    __syncthreads();
  }
}

extern "C" void kernel_launch(void* const* d_in, const int* in_sizes, int n_in,
                              void* d_out, int out_size, void* d_ws, size_t ws_size,
                              hipStream_t stream) {
  const float* x     = (const float*)d_in[0];
  const int*   src   = (const int*)d_in[1];
  const int*   dst   = (const int*)d_in[2];
  const float* w_gcn = (const float*)d_in[4];
  const float* b_gcn = (const float*)d_in[5];
  const float* w_ih  = (const float*)d_in[6];
  const float* w_hh  = (const float*)d_in[7];
  const float* b_ih  = (const float*)d_in[8];
  const float* b_hh  = (const float*)d_in[9];
  const float* w_fc  = (const float*)d_in[10];
  const float* b_fc  = (const float*)d_in[11];
  float* out = (float*)d_out;

  char* ws = (char*)d_ws;
  size_t off = 0;
  auto alloc = [&](size_t bytes) -> void* {
    void* p = ws + off; off += (bytes + 255) & ~(size_t)255; return p;
  };
  int* cnt     = (int*)alloc((size_t)N_GRAPHS*NPART*4);
  int* gtot    = (int*)alloc((size_t)N_GRAPHS*4);
  int* gbase   = (int*)alloc((size_t)N_GRAPHS*4);
  int* part    = (int*)alloc((size_t)N_EDGES_*4);
  unsigned short* sorted_all = (unsigned short*)alloc((size_t)N_EDGES_*2);
  int* e_end   = (int*)alloc((size_t)N_NODES_*4);
  int* e_deg   = (int*)alloc((size_t)N_NODES_*4);
  ushort4* xsb = (ushort4*)alloc((size_t)N_NODES_*DIN*2);
  unsigned short* hpreb = (unsigned short*)alloc((size_t)N_GRAPHS*NPGP*DIN*2);
  float* proj  = (float*)alloc((size_t)N_GRAPHS*G4*4);
  (void)ws_size; (void)in_sizes; (void)n_in; (void)out_size;

  void* args[] = { (void*)&src, (void*)&dst, (void*)&x, (void*)&cnt,
                   (void*)&gtot, (void*)&gbase, (void*)&part, (void*)&sorted_all,
                   (void*)&e_end, (void*)&e_deg, (void*)&xsb };
  hipLaunchCooperativeKernel((void*)k_prep, dim3(NPART), dim3(512), args, 0, stream);
  k_agg<<<(N_GRAPHS*NPGP)/4, 256, 0, stream>>>((const int4*)xsb, e_end, e_deg, sorted_all, hpreb);
  k_gcn<<<N_GRAPHS, 256, 0, stream>>>(hpreb, w_gcn, b_gcn, w_ih, b_ih, proj);
  k_lstm<<<BWIN, 512, 0, stream>>>(proj, w_hh, b_hh, w_fc, b_fc, out);
}

// Round 12
// 225.652 us; speedup vs baseline: 1.7483x; 1.7483x over previous
//
#include <hip/hip_runtime.h>
#include <hip/hip_bf16.h>

#define N_GRAPHS 200
#define NPG      500
#define NPGP     512                   // padded nodes per graph (MFMA tiles)
#define N_NODES_ 100000
#define N_EDGES_ 1600000
#define DIN      64
#define DG       128
#define SEQ      20
#define HL       128
#define G4       512
#define BWIN     (N_GRAPHS - SEQ + 1)  // 181
#define NPART    256
#define EPB      (N_EDGES_/NPART)      // 6250
#define CAP      9216                  // per-graph edge segment capacity
#define SLOTS    80                    // LDS bucket slots per graph per block

typedef __attribute__((ext_vector_type(8))) short short8;
typedef __attribute__((ext_vector_type(4))) float float4v;
typedef __attribute__((ext_vector_type(2))) _Float16 half2v;

__device__ __forceinline__ float sigmoidf_(float v){ return 1.0f/(1.0f+expf(-v)); }

// fp32 -> bf16 round-to-nearest-even
__device__ __forceinline__ unsigned short f2bf(float f) {
  unsigned int u = __float_as_uint(f);
  u += 0x7fffu + ((u >> 16) & 1u);
  return (unsigned short)(u >> 16);
}

__device__ __forceinline__ float h2dot(half2v a, half2v b, float c) {
#if __has_builtin(__builtin_amdgcn_fdot2)
  return __builtin_amdgcn_fdot2(a, b, c, false);
#else
  return c + (float)a.x*(float)b.x + (float)a.y*(float)b.y;
#endif
}

// K1: scan-free partition into fixed per-graph segments part[g*CAP ...].
// LDS bucket (80 slots/graph) -> one device atomicAdd per (block,graph) to
// reserve a base -> wave-per-graph coalesced flush. No k_count/k_pscan, no
// grid sync (round-11: grid.sync() ~25-30 us each — worse than a launch).
__global__ __launch_bounds__(256) void k_part(const int* __restrict__ src,
                                              const int* __restrict__ dst,
                                              int* __restrict__ gcount,
                                              int* __restrict__ part) {
  __shared__ int cnt[N_GRAPHS];
  __shared__ int base[N_GRAPHS];
  __shared__ int buf[N_GRAPHS][SLOTS];   // 64 KB
  int b = blockIdx.x, t = threadIdx.x;
  for (int g = t; g < N_GRAPHS; g += 256) cnt[g] = 0;
  __syncthreads();
  int e0 = b*EPB;
  for (int i = t; i < EPB; i += 256) {
    int s = src[e0+i], d = dst[e0+i];
    int g = s / NPG;
    int sl = s - g*NPG, dl = d - g*NPG;
    int pk = (sl << 9) | dl;
    int pos = atomicAdd(&cnt[g], 1);
    if (pos < SLOTS) buf[g][pos] = pk;
    else {                                // ultra-rare overflow (13-sigma)
      int gp = atomicAdd(&gcount[g], 1);
      part[g*CAP + gp] = pk;
    }
  }
  __syncthreads();
  if (t < N_GRAPHS) base[t] = atomicAdd(&gcount[t], min(cnt[t], SLOTS));
  __syncthreads();
  // flush: wave w handles graphs w, w+4, ...; lanes copy slots (coalesced runs)
  int w = t >> 6, lane = t & 63;
  for (int g = w; g < N_GRAPHS; g += 4) {
    int n = min(cnt[g], SLOTS);
    int ba = g*CAP + base[g];
    for (int j = lane; j < n; j += 64) part[ba + j] = buf[g][j];
  }
}

// K2: per-graph counting sort -> sorted src list + node metadata + xprep.
__global__ __launch_bounds__(512) void k_sort(const int* __restrict__ gcount,
    const int* __restrict__ part, const float* __restrict__ x,
    unsigned short* __restrict__ sorted_all,
    int* __restrict__ e_end, int* __restrict__ e_deg,
    ushort4* __restrict__ xsb) {
  __shared__ int indeg[NPG], outdeg[NPG], off[NPG];
  __shared__ float soS[NPG];
  __shared__ int sA[512], sB[512];
  int g = blockIdx.x, t = threadIdx.x;
  int seg0 = g*CAP;
  int seg1 = seg0 + gcount[g];
  if (t < NPG) { indeg[t] = 0; outdeg[t] = 0; }
  __syncthreads();
  for (int e = seg0 + t; e < seg1; e += 512) {
    int p = part[e];
    atomicAdd(&indeg[p & 511], 1);
    atomicAdd(&outdeg[p >> 9], 1);
  }
  __syncthreads();
  int v = (t < NPG) ? indeg[t] : 0;
  sA[t] = v; __syncthreads();
  int* cur = sA; int* nxt = sB;
  for (int o = 1; o < 512; o <<= 1) {
    nxt[t] = cur[t] + ((t >= o) ? cur[t-o] : 0);
    __syncthreads();
    int* tmp = cur; cur = nxt; nxt = tmp;
  }
  if (t < NPG) off[t] = cur[t] - v;
  __syncthreads();
  for (int e = seg0 + t; e < seg1; e += 512) {
    int p = part[e];
    int pos = atomicAdd(&off[p & 511], 1);
    sorted_all[seg0 + pos] = (unsigned short)(p >> 9);
  }
  __syncthreads();
  if (t < NPG) {
    soS[t] = rsqrtf((float)max(outdeg[t], 1));
    e_end[g*NPG + t] = seg0 + off[t];    // off now inclusive end
    e_deg[g*NPG + t] = indeg[t];
  }
  __syncthreads();
  // fused xprep: xsb[n][k] = bf16(x[n][k] * so[n])
  const float4* xg = ((const float4*)x) + (size_t)g*8000;   // 500*16
  ushort4* og = xsb + (size_t)g*8000;
  for (int i = t; i < 8000; i += 512) {
    float4 vv = xg[i];
    float s = soS[i >> 4];
    ushort4 u;
    u.x = f2bf(vv.x*s); u.y = f2bf(vv.y*s); u.z = f2bf(vv.z*s); u.w = f2bf(vv.w*s);
    og[i] = u;
  }
}

// K3: aggregation — wave per node slot; 8 lanes per edge (int4 = 8 bf16),
// 4-edge unroll per group. Packed-bf16 accumulate (exact). XCD swizzle.
__global__ __launch_bounds__(256) void k_agg(const int4* __restrict__ xsb,
    const int* __restrict__ e_end, const int* __restrict__ e_deg,
    const unsigned short* __restrict__ sorted_all,
    unsigned short* __restrict__ hpreb) {
  int b = blockIdx.x;
  int xcd = b & 7;
  int i_ = b >> 3;                       // 0..3199
  int g = (i_ >> 7)*8 + xcd;             // g % 8 == xcd
  int t = threadIdx.x;
  int nl = ((i_ & 127) << 2) + (t >> 6); // node slot 0..511 within graph
  int npad = g*NPGP + nl;
  int lane = t & 63, g8 = lane >> 3, fl = lane & 7;
  if (nl >= NPG) {                       // pad rows -> zeros
    if (g8 == 0) {
      int4 z = make_int4(0,0,0,0);
      ((int4*)hpreb)[(size_t)npad*8 + fl] = z;
    }
    return;
  }
  int n = g*NPG + nl;
  int end = e_end[n], deg = e_deg[n], start = end - deg;
  const int4* xg = xsb + (size_t)g*4000;      // 500 rows * 8 int4
  float aHi[4] = {0.f,0.f,0.f,0.f};
  float aLo[4] = {0.f,0.f,0.f,0.f};
  for (int i = start + (g8 << 2); i < end; i += 32) {
    int sj[4];
    #pragma unroll
    for (int j = 0; j < 4; ++j) sj[j] = (i + j < end) ? (int)sorted_all[i+j] : -1;
    #pragma unroll
    for (int j = 0; j < 4; ++j) if (sj[j] >= 0) {
      int4 v = xg[sj[j]*8 + fl];
      aHi[0] += __uint_as_float((unsigned)v.x & 0xffff0000u);
      aLo[0] += __uint_as_float((unsigned)v.x << 16);
      aHi[1] += __uint_as_float((unsigned)v.y & 0xffff0000u);
      aLo[1] += __uint_as_float((unsigned)v.y << 16);
      aHi[2] += __uint_as_float((unsigned)v.z & 0xffff0000u);
      aLo[2] += __uint_as_float((unsigned)v.z << 16);
      aHi[3] += __uint_as_float((unsigned)v.w & 0xffff0000u);
      aLo[3] += __uint_as_float((unsigned)v.w << 16);
    }
  }
  #pragma unroll
  for (int m = 8; m < 64; m <<= 1) {
    #pragma unroll
    for (int d = 0; d < 4; ++d) {
      aHi[d] += __shfl_xor(aHi[d], m);
      aLo[d] += __shfl_xor(aLo[d], m);
    }
  }
  if (g8 == 0) {
    float sn = rsqrtf((float)max(deg, 1));
    int4 outv;
    outv.x = (int)(((unsigned)f2bf(aLo[0]*sn)) | ((unsigned)f2bf(aHi[0]*sn) << 16));
    outv.y = (int)(((unsigned)f2bf(aLo[1]*sn)) | ((unsigned)f2bf(aHi[1]*sn) << 16));
    outv.z = (int)(((unsigned)f2bf(aLo[2]*sn)) | ((unsigned)f2bf(aHi[2]*sn) << 16));
    outv.w = (int)(((unsigned)f2bf(aLo[3]*sn)) | ((unsigned)f2bf(aHi[3]*sn) << 16));
    ((int4*)hpreb)[(size_t)npad*8 + fl] = outv;
  }
}

// K4: MFMA GCN GEMM + ReLU + mean pool + fused input projection.
__global__ __launch_bounds__(256) void k_gcn(
    const unsigned short* __restrict__ hpreb,
    const float* __restrict__ w_gcn,
    const float* __restrict__ b_gcn,
    const float* __restrict__ w_ih,
    const float* __restrict__ b_ih,
    float* __restrict__ proj) {
  __shared__ unsigned short wLds[16*64*8];   // 16 KB
  __shared__ float pS[4*DG];
  __shared__ __align__(16) float hgS[DG];
  int t = threadIdx.x, g = blockIdx.x;
  for (int idx = t; idx < 16*64; idx += 256) {
    int f = idx >> 6, l = idx & 63;
    int h = f & 1, nt = f >> 1;
    int kbase = h*32 + (l >> 4)*8;
    int n = nt*16 + (l & 15);
    #pragma unroll
    for (int j = 0; j < 8; ++j)
      wLds[idx*8 + j] = f2bf(w_gcn[(kbase + j)*DG + n]);
  }
  __syncthreads();
  int w = t >> 6, lane = t & 63;
  int quad = lane >> 4, l15 = lane & 15;
  float bcol[8];
  #pragma unroll
  for (int nt = 0; nt < 8; ++nt) bcol[nt] = b_gcn[nt*16 + l15];
  float psum[8] = {0.f,0.f,0.f,0.f,0.f,0.f,0.f,0.f};
  const unsigned short* hb = hpreb + (size_t)g*NPGP*DIN;
  for (int i = 0; i < 8; ++i) {
    int rt = w + 4*i;
    int row0 = rt*16;
    const short8* aptr = (const short8*)(hb + (size_t)(row0 + l15)*DIN + quad*8);
    short8 a0 = aptr[0];
    short8 a1 = aptr[4];
    #pragma unroll
    for (int nt = 0; nt < 8; ++nt) {
      short8 b0 = *((const short8*)&wLds[((nt*2+0)*64 + lane)*8]);
      short8 b1 = *((const short8*)&wLds[((nt*2+1)*64 + lane)*8]);
      float4v acc = {0.f, 0.f, 0.f, 0.f};
      acc = __builtin_amdgcn_mfma_f32_16x16x32_bf16(a0, b0, acc, 0, 0, 0);
      acc = __builtin_amdgcn_mfma_f32_16x16x32_bf16(a1, b1, acc, 0, 0, 0);
      #pragma unroll
      for (int r = 0; r < 4; ++r) {
        int node = row0 + quad*4 + r;
        float v = acc[r] + bcol[nt];
        psum[nt] += (node < NPG) ? fmaxf(v, 0.f) : 0.f;
      }
    }
  }
  #pragma unroll
  for (int nt = 0; nt < 8; ++nt) {
    float v = psum[nt];
    v += __shfl_xor(v, 16);
    v += __shfl_xor(v, 32);
    if (lane < 16) pS[w*DG + nt*16 + lane] = v;
  }
  __syncthreads();
  if (t < DG)
    hgS[t] = (pS[t] + pS[DG+t] + pS[2*DG+t] + pS[3*DG+t]) * (1.0f/NPG);
  __syncthreads();
  for (int r = t; r < G4; r += 256) {
    const float4* wr = (const float4*)(w_ih + (size_t)r*HL);
    const float4* hv = (const float4*)hgS;
    float acc = b_ih[r];
    #pragma unroll
    for (int k4 = 0; k4 < 32; ++k4) {
      float4 w4 = wr[k4]; float4 h4 = hv[k4];
      acc += w4.x*h4.x + w4.y*h4.y + w4.z*h4.z + w4.w*h4.w;
    }
    proj[(size_t)g*G4 + r] = acc;
  }
}

// K5: LSTM — w_hh fp16 CU-resident in LDS; h packed fp16; fp32 accumulation.
__global__ __launch_bounds__(512) void k_lstm(const float* __restrict__ proj,
    const float* __restrict__ w_hh, const float* __restrict__ b_hh,
    const float* __restrict__ w_fc, const float* __restrict__ b_fc,
    float* __restrict__ out) {
  __shared__ int4 wL[16*512];        // 128 KB: [k4][r] = 8 fp16 of w_hh[r][k4*8..]
  __shared__ float gS[G4];
  __shared__ __align__(16) int4 hPi[16];  // 128 fp16 packed h state
  int b = blockIdx.x, t = threadIdx.x;
  for (int i = t; i < 16*512; i += 512) {
    int k4 = i >> 9, r = i & 511;
    const float4* wp = (const float4*)(w_hh + (size_t)r*HL + k4*8);
    float4 w0 = wp[0], w1 = wp[1];
    half2v p0 = {(_Float16)w0.x, (_Float16)w0.y};
    half2v p1 = {(_Float16)w0.z, (_Float16)w0.w};
    half2v p2 = {(_Float16)w1.x, (_Float16)w1.y};
    half2v p3 = {(_Float16)w1.z, (_Float16)w1.w};
    int4 pk;
    pk.x = __builtin_bit_cast(int, p0); pk.y = __builtin_bit_cast(int, p1);
    pk.z = __builtin_bit_cast(int, p2); pk.w = __builtin_bit_cast(int, p3);
    wL[i] = pk;
  }
  if (t < 16) hPi[t] = make_int4(0,0,0,0);
  float bh = b_hh[t];
  float c0 = 0.f, c1 = 0.f;
  __syncthreads();
  for (int l = 0; l < SEQ; ++l) {
    float acc = proj[(size_t)(b+l)*G4 + t] + bh;
    #pragma unroll
    for (int k4 = 0; k4 < 16; ++k4) {
      int4 wv = wL[(k4 << 9) + t];
      int4 hv = hPi[k4];
      acc = h2dot(__builtin_bit_cast(half2v, wv.x), __builtin_bit_cast(half2v, hv.x), acc);
      acc = h2dot(__builtin_bit_cast(half2v, wv.y), __builtin_bit_cast(half2v, hv.y), acc);
      acc = h2dot(__builtin_bit_cast(half2v, wv.z), __builtin_bit_cast(half2v, hv.z), acc);
      acc = h2dot(__builtin_bit_cast(half2v, wv.w), __builtin_bit_cast(half2v, hv.w), acc);
    }
    gS[t] = acc;
    __syncthreads();
    if (t < 64) {
      int j0 = 2*t, j1 = 2*t + 1;
      float i0 = sigmoidf_(gS[j0]),      i1 = sigmoidf_(gS[j1]);
      float f0 = sigmoidf_(gS[HL+j0]),   f1 = sigmoidf_(gS[HL+j1]);
      float g0 = tanhf(gS[2*HL+j0]),     g1 = tanhf(gS[2*HL+j1]);
      float o0 = sigmoidf_(gS[3*HL+j0]), o1 = sigmoidf_(gS[3*HL+j1]);
      c0 = f0*c0 + i0*g0;
      c1 = f1*c1 + i1*g1;
      float h0 = o0 * tanhf(c0);
      float h1 = o1 * tanhf(c1);
      half2v hp = {(_Float16)h0, (_Float16)h1};
      ((int*)hPi)[t] = __builtin_bit_cast(int, hp);
      if (l == SEQ-1) {
        float s = h0*w_fc[j0] + h1*w_fc[j1];
        #pragma unroll
        for (int off = 32; off > 0; off >>= 1) s += __shfl_down(s, off);
        if (t == 0) out[b] = s + b_fc[0];
      }
    }
    __syncthreads();
  }
}

extern "C" void kernel_launch(void* const* d_in, const int* in_sizes, int n_in,
                              void* d_out, int out_size, void* d_ws, size_t ws_size,
                              hipStream_t stream) {
  const float* x     = (const float*)d_in[0];
  const int*   src   = (const int*)d_in[1];
  const int*   dst   = (const int*)d_in[2];
  const float* w_gcn = (const float*)d_in[4];
  const float* b_gcn = (const float*)d_in[5];
  const float* w_ih  = (const float*)d_in[6];
  const float* w_hh  = (const float*)d_in[7];
  const float* b_ih  = (const float*)d_in[8];
  const float* b_hh  = (const float*)d_in[9];
  const float* w_fc  = (const float*)d_in[10];
  const float* b_fc  = (const float*)d_in[11];
  float* out = (float*)d_out;

  char* ws = (char*)d_ws;
  size_t off = 0;
  auto alloc = [&](size_t bytes) -> void* {
    void* p = ws + off; off += (bytes + 255) & ~(size_t)255; return p;
  };
  int* gcount  = (int*)alloc((size_t)N_GRAPHS*4);
  int* part    = (int*)alloc((size_t)N_GRAPHS*CAP*4);
  unsigned short* sorted_all = (unsigned short*)alloc((size_t)N_GRAPHS*CAP*2);
  int* e_end   = (int*)alloc((size_t)N_NODES_*4);
  int* e_deg   = (int*)alloc((size_t)N_NODES_*4);
  ushort4* xsb = (ushort4*)alloc((size_t)N_NODES_*DIN*2);
  unsigned short* hpreb = (unsigned short*)alloc((size_t)N_GRAPHS*NPGP*DIN*2);
  float* proj  = (float*)alloc((size_t)N_GRAPHS*G4*4);
  (void)ws_size; (void)in_sizes; (void)n_in; (void)out_size;

  hipMemsetAsync(gcount, 0, (size_t)N_GRAPHS*4, stream);
  k_part<<<NPART, 256, 0, stream>>>(src, dst, gcount, part);
  k_sort<<<N_GRAPHS, 512, 0, stream>>>(gcount, part, x, sorted_all, e_end, e_deg, xsb);
  k_agg<<<(N_GRAPHS*NPGP)/4, 256, 0, stream>>>((const int4*)xsb, e_end, e_deg, sorted_all, hpreb);
  k_gcn<<<N_GRAPHS, 256, 0, stream>>>(hpreb, w_gcn, b_gcn, w_ih, b_ih, proj);
  k_lstm<<<BWIN, 512, 0, stream>>>(proj, w_hh, b_hh, w_fc, b_fc, out);
}